// Round 6
// baseline (325.538 us; speedup 1.0000x reference)
//
#include <hip/hip_runtime.h>

#define SEQ 4096
#define HID 1024

typedef _Float16 f16x4 __attribute__((ext_vector_type(4)));
typedef _Float16 f16x8 __attribute__((ext_vector_type(8)));
typedef float    f32x4 __attribute__((ext_vector_type(4)));

// ---------- async global->LDS, 16B per lane ----------
__device__ __forceinline__ void gld16(const void* g, void* l) {
    __builtin_amdgcn_global_load_lds(
        (const __attribute__((address_space(1))) unsigned int*)g,
        (__attribute__((address_space(3))) unsigned int*)l, 16, 0, 0);
}

// ---------- fp32 -> fp16 cast (6 tensors) + zero out_x + zero rowsum ----------
__global__ __launch_bounds__(256) void cast_all(
    const float4* __restrict__ q, const float4* __restrict__ k,
    const float4* __restrict__ v,
    const float4* __restrict__ wq, const float4* __restrict__ wk,
    const float4* __restrict__ wv,
    f16x4* __restrict__ qh, f16x4* __restrict__ kh, f16x4* __restrict__ vh,
    f16x4* __restrict__ wqh, f16x4* __restrict__ wkh, f16x4* __restrict__ wvh,
    float4* __restrict__ zx, float4* __restrict__ zr,
    int nX4, int nW4, int nZ4, int nR4) {
    int t = blockIdx.x * 256 + threadIdx.x;
    const float4 *a, *b, *c; f16x4 *da, *db, *dc; int idx;
    if (t < nX4) { a = q; b = k; c = v; da = qh; db = kh; dc = vh; idx = t; }
    else if (t < nX4 + nW4) {
        idx = t - nX4;
        a = wq; b = wk; c = wv; da = wqh; db = wkh; dc = wvh;
    } else {
        idx = t - nX4 - nW4;
        float4 z = {0.f, 0.f, 0.f, 0.f};
        if (idx < nZ4) zx[idx] = z;
        else if (idx < nZ4 + nR4) zr[idx - nZ4] = z;
        return;
    }
    float4 va = a[idx], vb = b[idx], vc = c[idx];
    f16x4 oa = {(_Float16)va.x, (_Float16)va.y, (_Float16)va.z, (_Float16)va.w};
    f16x4 ob = {(_Float16)vb.x, (_Float16)vb.y, (_Float16)vb.z, (_Float16)vb.w};
    f16x4 oc = {(_Float16)vc.x, (_Float16)vc.y, (_Float16)vc.z, (_Float16)vc.w};
    da[idx] = oa; db[idx] = ob; dc[idx] = oc;
}

// ---------- NT GEMM: C[M,N] = scale * A[M,K] @ Bt[N,K]^T ----------
// 128x128 tile, BK=64 staged as two 128x32 sub-tiles, one barrier pair / 64-K.
// TRI_SKIP: skip blocks strictly above the diagonal.
// TRI_K:    K-loop only to (bm+1)*128 (PV with lower-triangular expE).
// ZMODE: 0 = plain store
//        1 = z-batched (ptr += z*stride); aux = VT, z==2 also writes V^T
//        2 = split-K over z (chunk KC); aux = rowsum; epilogue scales by
//            scale/rowsum[row]; atomicAdd unless single-writer tile
//        3 = energy: epilogue stores expE=exp(acc*scale-4) f16 (col<=row
//            else 0) and atomicAdds per-row partial sums into aux=rowsum
template <typename OutT, bool TRI_SKIP, bool TRI_K, int ZMODE>
__global__ __launch_bounds__(256) void gemm_nt(
    const _Float16* __restrict__ A, const _Float16* __restrict__ Bt,
    OutT* __restrict__ C, int M, int N, int K, float scale,
    long sA, long sB, long sC, int KC, void* aux) {
    __shared__ __attribute__((aligned(16))) _Float16 As[2 * 128 * 32];
    __shared__ __attribute__((aligned(16))) _Float16 Bs[2 * 128 * 32];

    const int bm = blockIdx.y, bn = blockIdx.x;
    if (TRI_SKIP && bn > bm) return;
    if (ZMODE == 1) {
        A  += (long)blockIdx.z * sA;
        Bt += (long)blockIdx.z * sB;
        C  += (long)blockIdx.z * sC;
    }
    int kend = TRI_K ? min(K, (bm + 1) * 128) : K;
    int kstart = 0;
    bool single = false;
    if (ZMODE == 2) {
        kstart = blockIdx.z * KC;
        if (kstart >= kend) return;
        single = (kend <= KC);          // only z=0 writes this tile
        kend = min(kend, kstart + KC);
    }

    const int tid = threadIdx.x;
    const int tr  = tid >> 2;            // 0..63
    const int tc8 = (tid & 3) * 8;       // 0,8,16,24  (f16 elements)

    const _Float16* Ab = A  + (size_t)bm * 128 * K;
    const _Float16* Bb = Bt + (size_t)bn * 128 * K;

    const int wave = tid >> 6;
    const int lane = tid & 63;
    const int wm = (wave >> 1) * 64;     // wave row offset in tile
    const int wn = (wave & 1) * 64;      // wave col offset in tile
    const int lr = lane & 15;            // row (A) / col (B) within 16
    const int lk = (lane >> 4) * 8;      // k offset within 32

    f32x4 acc[4][4];
#pragma unroll
    for (int i = 0; i < 4; ++i)
#pragma unroll
        for (int j = 0; j < 4; ++j) acc[i][j] = (f32x4)0.0f;

    for (int k0 = kstart; k0 < kend; k0 += 64) {
#pragma unroll
        for (int h = 0; h < 2; ++h) {
            const int kk = k0 + h * 32, off = h * 4096;
            gld16(Ab + (size_t)tr * K        + kk + tc8, &As[off + tr * 32 + tc8]);
            gld16(Ab + (size_t)(64 + tr) * K + kk + tc8, &As[off + (64 + tr) * 32 + tc8]);
            gld16(Bb + (size_t)tr * K        + kk + tc8, &Bs[off + tr * 32 + tc8]);
            gld16(Bb + (size_t)(64 + tr) * K + kk + tc8, &Bs[off + (64 + tr) * 32 + tc8]);
        }
        __syncthreads();

#pragma unroll
        for (int h = 0; h < 2; ++h) {
            const int off = h * 4096;
            f16x8 af[4], bfr[4];
#pragma unroll
            for (int i = 0; i < 4; ++i)
                af[i] = *(const f16x8*)&As[off + (wm + i * 16 + lr) * 32 + lk];
#pragma unroll
            for (int j = 0; j < 4; ++j)
                bfr[j] = *(const f16x8*)&Bs[off + (wn + j * 16 + lr) * 32 + lk];
#pragma unroll
            for (int i = 0; i < 4; ++i)
#pragma unroll
                for (int j = 0; j < 4; ++j)
                    acc[i][j] = __builtin_amdgcn_mfma_f32_16x16x32_f16(
                        af[i], bfr[j], acc[i][j], 0, 0, 0);
        }
        __syncthreads();
    }

    // epilogue: D row = (lane>>4)*4 + r, col = lane&15  [m89-verified]
    const int er = (lane >> 4) * 4;
    const int ec = lane & 15;

    if (ZMODE == 3) {
        float* rowsum = (float*)aux;
#pragma unroll
        for (int i = 0; i < 4; ++i) {
#pragma unroll
            for (int r = 0; r < 4; ++r) {
                const int row = bm * 128 + wm + i * 16 + er + r;
                float rs = 0.0f;
#pragma unroll
                for (int j = 0; j < 4; ++j) {
                    const int col = bn * 128 + wn + j * 16 + ec;
                    float e = (col <= row) ? __expf(acc[i][j][r] * scale - 4.0f) : 0.0f;
                    C[(size_t)row * N + col] = (OutT)e;
                    rs += e;
                }
                rs += __shfl_xor(rs, 1, 64);
                rs += __shfl_xor(rs, 2, 64);
                rs += __shfl_xor(rs, 4, 64);
                rs += __shfl_xor(rs, 8, 64);
                if (ec == 0) atomicAdd(&rowsum[row], rs);
            }
        }
    } else if (ZMODE == 2) {
        const float* rowsum = (const float*)aux;
#pragma unroll
        for (int i = 0; i < 4; ++i) {
#pragma unroll
            for (int r = 0; r < 4; ++r) {
                const int row = bm * 128 + wm + i * 16 + er + r;
                const float inv = scale / rowsum[row];
#pragma unroll
                for (int j = 0; j < 4; ++j) {
                    const int col = bn * 128 + wn + j * 16 + ec;
                    const size_t idx = (size_t)row * N + col;
                    const float val = acc[i][j][r] * inv;
                    if (!single) atomicAdd((float*)&C[idx], val);
                    else          C[idx] = (OutT)val;
                }
            }
        }
    } else {
        _Float16* VT = (ZMODE == 1) ? (_Float16*)aux : nullptr;
#pragma unroll
        for (int i = 0; i < 4; ++i) {
#pragma unroll
            for (int j = 0; j < 4; ++j) {
                const int row0 = bm * 128 + wm + i * 16 + er;
                const int col  = bn * 128 + wn + j * 16 + ec;
#pragma unroll
                for (int r = 0; r < 4; ++r)
                    C[(size_t)(row0 + r) * N + col] = (OutT)(acc[i][j][r] * scale);
                if (ZMODE == 1 && blockIdx.z == 2) {   // V: also write V^T
                    f16x4 pv = {(_Float16)acc[i][j][0], (_Float16)acc[i][j][1],
                                (_Float16)acc[i][j][2], (_Float16)acc[i][j][3]};
                    *(f16x4*)&VT[(size_t)col * M + row0] = pv;
                }
            }
        }
    }
}

// ---------- att[i][j] = (j<=i) ? expE[i][j]/rowsum[i] : 0 ----------
// grid (SEQ/2048, SEQ), 8 elems/thread; 8-chunks never cross 128-tile
// boundaries so any chunk with c0<=i reads only energy-written memory.
__global__ __launch_bounds__(256) void rescale_att(
    const _Float16* __restrict__ EP, const float* __restrict__ rowsum,
    float* __restrict__ att) {
    const int i  = blockIdx.y;
    const int c0 = blockIdx.x * 2048 + threadIdx.x * 8;
    float* arow = att + (size_t)i * SEQ;
    if (c0 > i) {
        float4 z = {0.f, 0.f, 0.f, 0.f};
        *(float4*)&arow[c0]     = z;
        *(float4*)&arow[c0 + 4] = z;
        return;
    }
    const float rinv = 1.0f / rowsum[i];
    f16x8 e8 = *(const f16x8*)&EP[(size_t)i * SEQ + c0];
    float4 a0, a1;
    a0.x = (c0 + 0 <= i) ? (float)e8[0] * rinv : 0.f;
    a0.y = (c0 + 1 <= i) ? (float)e8[1] * rinv : 0.f;
    a0.z = (c0 + 2 <= i) ? (float)e8[2] * rinv : 0.f;
    a0.w = (c0 + 3 <= i) ? (float)e8[3] * rinv : 0.f;
    a1.x = (c0 + 4 <= i) ? (float)e8[4] * rinv : 0.f;
    a1.y = (c0 + 5 <= i) ? (float)e8[5] * rinv : 0.f;
    a1.z = (c0 + 6 <= i) ? (float)e8[6] * rinv : 0.f;
    a1.w = (c0 + 7 <= i) ? (float)e8[7] * rinv : 0.f;
    *(float4*)&arow[c0]     = a0;
    *(float4*)&arow[c0 + 4] = a1;
}

extern "C" void kernel_launch(void* const* d_in, const int* in_sizes, int n_in,
                              void* d_out, int out_size, void* d_ws, size_t ws_size,
                              hipStream_t stream) {
    const float* q  = (const float*)d_in[0];
    const float* k  = (const float*)d_in[1];
    const float* v  = (const float*)d_in[2];
    // d_in[3] = mask: causal tril by construction -> handled analytically
    const float* Wq = (const float*)d_in[4];
    const float* Wk = (const float*)d_in[5];
    const float* Wv = (const float*)d_in[6];

    float* out_x   = (float*)d_out;                       // [SEQ, HID]
    float* out_att = out_x + (size_t)SEQ * HID;           // [SEQ, SEQ]

    char* ws = (char*)d_ws;
    const size_t SH = (size_t)SEQ * HID * sizeof(_Float16);   // 8 MiB
    const size_t HH = (size_t)HID * HID * sizeof(_Float16);   // 2 MiB
    _Float16* qh  = (_Float16*)(ws);                      // qh,kh,vh contiguous
    _Float16* kh  = (_Float16*)(ws + SH);
    _Float16* vh  = (_Float16*)(ws + 2 * SH);
    _Float16* wqh = (_Float16*)(ws + 3 * SH);             // wqh,wkh,wvh contiguous
    _Float16* wkh = (_Float16*)(ws + 3 * SH + HH);
    _Float16* wvh = (_Float16*)(ws + 3 * SH + 2 * HH);
    _Float16* Qh  = (_Float16*)(ws + 3 * SH + 3 * HH);    // Qh,Kh,Vh contiguous
    _Float16* Kh  = (_Float16*)(ws + 4 * SH + 3 * HH);
    _Float16* Vh  = (_Float16*)(ws + 5 * SH + 3 * HH);
    _Float16* VT  = (_Float16*)(ws + 6 * SH + 3 * HH);    // [HID][SEQ] f16
    _Float16* EP  = (_Float16*)(ws + 7 * SH + 3 * HH);    // [SEQ][SEQ] f16 expE
    float*  rowsum = (float*)(ws + 7 * SH + 3 * HH + (size_t)SEQ * SEQ * 2);

    // 1) casts + zero out_x + zero rowsum, one launch
    const int nX4 = SEQ * HID / 4, nW4 = HID * HID / 4;
    const int nZ4 = SEQ * HID / 4, nR4 = SEQ / 4;
    cast_all<<<(nX4 + nW4 + nZ4 + nR4 + 255) / 256, 256, 0, stream>>>(
        (const float4*)q, (const float4*)k, (const float4*)v,
        (const float4*)Wq, (const float4*)Wk, (const float4*)Wv,
        (f16x4*)qh, (f16x4*)kh, (f16x4*)vh,
        (f16x4*)wqh, (f16x4*)wkh, (f16x4*)wvh,
        (float4*)out_x, (float4*)rowsum, nX4, nW4, nZ4, nR4);

    // 2) projections Q/K/V = X @ W.T, z-batched; z==2 also emits V^T
    gemm_nt<_Float16, false, false, 1><<<dim3(HID / 128, SEQ / 128, 3), 256, 0, stream>>>(
        qh, wqh, Qh, SEQ, HID, HID, 1.0f,
        (long)SEQ * HID, (long)HID * HID, (long)SEQ * HID, 0, VT);

    // 3) energy: expE = exp(QK^T/32 - 4) f16 (lower tiles) + rowsum atomics
    gemm_nt<_Float16, true, false, 3><<<dim3(SEQ / 128, SEQ / 128), 256, 0, stream>>>(
        Qh, Kh, EP, SEQ, SEQ, HID, 0.03125f, 0, 0, 0, 0, rowsum);

    // 4) attention output: elementwise expE/rowsum -> f32 d_out
    rescale_att<<<dim3(SEQ / 2048, SEQ), 256, 0, stream>>>(EP, rowsum, out_att);

    // 5) x = (expE @ V) / rowsum, split-K z=4 (KC=1024), atomic f32 epilogue
    gemm_nt<float, false, true, 2><<<dim3(HID / 128, SEQ / 128, 4), 256, 0, stream>>>(
        EP, VT, out_x, SEQ, HID, SEQ, 1.0f, 0, 0, 0, 1024, rowsum);
}